// Round 1
// baseline (288.244 us; speedup 1.0000x reference)
//
#include <hip/hip_runtime.h>
#include <hip/hip_bf16.h>

#define D_ 1024
#define NSEQ 2048
#define NB 4
#define NTOK 8192

typedef __attribute__((ext_vector_type(8))) short bf16x8;
typedef __attribute__((ext_vector_type(4))) float f32x4;

static __device__ __forceinline__ unsigned short f2bf(float x) {
    union { __hip_bfloat16 h; unsigned short u; } cv;
    cv.h = __float2bfloat16(x);
    return cv.u;
}

// ---------------- x fp32 -> bf16 ----------------
__global__ __launch_bounds__(256) void cvt_x(const float* __restrict__ x,
                                             __hip_bfloat16* __restrict__ xb) {
    int i = blockIdx.x * 256 + threadIdx.x;           // 8192*256 threads, 4 elems each
    float4 v = reinterpret_cast<const float4*>(x)[i];
    ushort4 o;
    o.x = f2bf(v.x); o.y = f2bf(v.y); o.z = f2bf(v.z); o.w = f2bf(v.w);
    reinterpret_cast<ushort4*>(xb)[i] = o;
}

// ---------------- W [d][e] fp32 -> Wt [e][d] bf16 (3 weights via z) ----------------
__global__ __launch_bounds__(256) void wt_kernel(const float* __restrict__ Wq,
                                                 const float* __restrict__ Wk,
                                                 const float* __restrict__ Wv,
                                                 __hip_bfloat16* __restrict__ Wt) {
    const float* W = (blockIdx.z == 0) ? Wq : (blockIdx.z == 1) ? Wk : Wv;
    unsigned short* O = (unsigned short*)(Wt + (size_t)blockIdx.z * D_ * D_);
    __shared__ float tile[32][33];
    int r0 = blockIdx.y * 32, c0 = blockIdx.x * 32;
    int t = threadIdx.x;
    int r = t >> 3, c4 = (t & 7) * 4;
    float4 v = *reinterpret_cast<const float4*>(&W[(size_t)(r0 + r) * D_ + c0 + c4]);
    tile[r][c4 + 0] = v.x; tile[r][c4 + 1] = v.y;
    tile[r][c4 + 2] = v.z; tile[r][c4 + 3] = v.w;
    __syncthreads();
    int er = t >> 3, dc = (t & 7) * 4;   // write Wt[c0+er][r0+dc .. +3] = W[r0+dc+i][c0+er]
    ushort4 pk;
    pk.x = f2bf(tile[dc + 0][er]); pk.y = f2bf(tile[dc + 1][er]);
    pk.z = f2bf(tile[dc + 2][er]); pk.w = f2bf(tile[dc + 3][er]);
    *reinterpret_cast<ushort4*>(&O[(size_t)(c0 + er) * D_ + r0 + dc]) = pk;
}

// ---------------- NT GEMM: C[M][N] = A[M][K] * Bt[N][K]^T ----------------
// BM=BN=64, BK=32, 256 threads = 4 waves (2x2), each wave 32x32 (2x2 frags of 16x16).
// MODE 0: bf16 C row-major (ldc=1024)             [Q, K projections]
// MODE 1: bf16 written transposed per batch -> Vt [V projection]
// MODE 2: scores: fp32, *1/32, causal mask, skip upper blocks, per-batch z
// MODE 3: PV: fp32 out * rinv[q], K-extent = (bx+1)*64, per-batch z
template <int MODE>
__global__ __launch_bounds__(256) void gemm_nt(const __hip_bfloat16* __restrict__ A, int lda,
                                               const __hip_bfloat16* __restrict__ Bt, int ldb,
                                               void* __restrict__ Cout,
                                               const float* __restrict__ rinv) {
    int bx = blockIdx.x, by = blockIdx.y, bz = blockIdx.z;
    if (MODE == 2 && by > bx) return;   // fully masked tile, never read downstream

    const __hip_bfloat16* Ab = A;
    const __hip_bfloat16* Bb = Bt;
    int Kdim = 1024;
    if (MODE == 2) {
        Ab = A + (size_t)bz * NSEQ * D_;
        Bb = Bt + (size_t)bz * NSEQ * D_;
    } else if (MODE == 3) {
        Ab = A + (size_t)bz * NSEQ * 4096;     // P rows, stride 4096 bf16 (in-place over S)
        Bb = Bt + (size_t)bz * D_ * NSEQ;      // Vt per batch
        Kdim = (bx + 1) * 64;                  // causal extent for this q-block
    }
    int m0 = bx * 64, n0 = by * 64;

    __shared__ __hip_bfloat16 As[64][40];   // 80B row stride: 16B aligned, 2-way bank alias
    __shared__ __hip_bfloat16 Bs[64][40];

    int tid = threadIdx.x;
    int lane = tid & 63, wid = tid >> 6;
    int wm = wid >> 1, wn = wid & 1;
    int lr = lane & 15, lk = lane >> 4;
    int srow = tid >> 2, sc = (tid & 3) * 8;

    f32x4 acc[2][2] = {};

    for (int k0 = 0; k0 < Kdim; k0 += 32) {
        __syncthreads();
        *reinterpret_cast<bf16x8*>(&As[srow][sc]) =
            *reinterpret_cast<const bf16x8*>(&Ab[(size_t)(m0 + srow) * lda + k0 + sc]);
        *reinterpret_cast<bf16x8*>(&Bs[srow][sc]) =
            *reinterpret_cast<const bf16x8*>(&Bb[(size_t)(n0 + srow) * ldb + k0 + sc]);
        __syncthreads();

        bf16x8 af0 = *reinterpret_cast<const bf16x8*>(&As[wm * 32 + lr][lk * 8]);
        bf16x8 af1 = *reinterpret_cast<const bf16x8*>(&As[wm * 32 + 16 + lr][lk * 8]);
        bf16x8 bf0 = *reinterpret_cast<const bf16x8*>(&Bs[wn * 32 + lr][lk * 8]);
        bf16x8 bf1 = *reinterpret_cast<const bf16x8*>(&Bs[wn * 32 + 16 + lr][lk * 8]);

        acc[0][0] = __builtin_amdgcn_mfma_f32_16x16x32_bf16(af0, bf0, acc[0][0], 0, 0, 0);
        acc[0][1] = __builtin_amdgcn_mfma_f32_16x16x32_bf16(af0, bf1, acc[0][1], 0, 0, 0);
        acc[1][0] = __builtin_amdgcn_mfma_f32_16x16x32_bf16(af1, bf0, acc[1][0], 0, 0, 0);
        acc[1][1] = __builtin_amdgcn_mfma_f32_16x16x32_bf16(af1, bf1, acc[1][1], 0, 0, 0);
    }

#pragma unroll
    for (int m = 0; m < 2; ++m)
#pragma unroll
        for (int n = 0; n < 2; ++n) {
            int rbase = m0 + wm * 32 + m * 16 + lk * 4;   // +j
            int cbase = n0 + wn * 32 + n * 16 + lr;
            if (MODE == 0) {
                unsigned short* C = (unsigned short*)Cout;
#pragma unroll
                for (int j = 0; j < 4; ++j)
                    C[(size_t)(rbase + j) * D_ + cbase] = f2bf(acc[m][n][j]);
            } else if (MODE == 1) {
                int b = rbase >> 11, nq = rbase & 2047;   // rbase multiple of 4: same batch
                ushort4 pk;
                pk.x = f2bf(acc[m][n][0]); pk.y = f2bf(acc[m][n][1]);
                pk.z = f2bf(acc[m][n][2]); pk.w = f2bf(acc[m][n][3]);
                *reinterpret_cast<ushort4*>(
                    &((unsigned short*)Cout)[((size_t)b * D_ + cbase) * NSEQ + nq]) = pk;
            } else if (MODE == 2) {
                float* S = (float*)Cout + (size_t)bz * NSEQ * NSEQ;
#pragma unroll
                for (int j = 0; j < 4; ++j) {
                    int qg = rbase + j, kg = cbase;
                    float s = acc[m][n][j] * 0.03125f;    // 1/sqrt(1024)
                    if (kg > qg) s = -1e30f;
                    S[(size_t)qg * NSEQ + kg] = s;
                }
            } else {
                float* O = (float*)Cout + (size_t)bz * NSEQ * D_;
#pragma unroll
                for (int j = 0; j < 4; ++j)
                    O[(size_t)(rbase + j) * D_ + cbase] =
                        acc[m][n][j] * rinv[bz * NSEQ + rbase + j];
            }
        }
}

// ---------------- row softmax: max, exp, sum; write unnormalized P bf16 in place ----------------
__global__ __launch_bounds__(256) void softmax_rows(float* __restrict__ S,
                                                    float* __restrict__ rinv) {
    int lane = threadIdx.x & 63;
    int row = blockIdx.x * 4 + (threadIdx.x >> 6);   // 0..8191
    int q = row & 2047;
    float* srow = S + (size_t)row * NSEQ;
    int L = ((q >> 6) + 1) << 6;                     // valid+masked extent (multiple of 64)

    float mx = -1e30f;
    for (int k = lane * 4; k < L; k += 256) {
        float4 v = *reinterpret_cast<const float4*>(srow + k);
        mx = fmaxf(mx, fmaxf(fmaxf(v.x, v.y), fmaxf(v.z, v.w)));
    }
    for (int off = 32; off > 0; off >>= 1) mx = fmaxf(mx, __shfl_xor(mx, off, 64));

    float sum = 0.f;
    unsigned short* prow = (unsigned short*)srow;    // in-place: bf16 writes trail fp32 reads
    for (int k = lane * 4; k < L; k += 256) {
        float4 v = *reinterpret_cast<const float4*>(srow + k);
        float e0 = __expf(v.x - mx), e1 = __expf(v.y - mx);
        float e2 = __expf(v.z - mx), e3 = __expf(v.w - mx);
        sum += (e0 + e1) + (e2 + e3);
        ushort4 pk; pk.x = f2bf(e0); pk.y = f2bf(e1); pk.z = f2bf(e2); pk.w = f2bf(e3);
        *reinterpret_cast<ushort4*>(prow + k) = pk;
    }
    for (int off = 32; off > 0; off >>= 1) sum += __shfl_xor(sum, off, 64);
    if (lane == 0) rinv[row] = 1.0f / sum;
}

extern "C" void kernel_launch(void* const* d_in, const int* in_sizes, int n_in,
                              void* d_out, int out_size, void* d_ws, size_t ws_size,
                              hipStream_t stream) {
    const float* x  = (const float*)d_in[0];
    const float* Wq = (const float*)d_in[1];
    const float* Wk = (const float*)d_in[2];
    const float* Wv = (const float*)d_in[3];

    char* ws = (char*)d_ws;
    float*          S    = (float*)(ws);                        // 4*2048*2048*4  = 64 MiB
    __hip_bfloat16* Xb   = (__hip_bfloat16*)(ws + 67108864);    // 16 MiB
    __hip_bfloat16* Q    = (__hip_bfloat16*)(ws + 83886080);    // 16 MiB
    __hip_bfloat16* K    = (__hip_bfloat16*)(ws + 100663296);   // 16 MiB
    __hip_bfloat16* Vt   = (__hip_bfloat16*)(ws + 117440512);   // 16 MiB
    __hip_bfloat16* Wt   = (__hip_bfloat16*)(ws + 134217728);   // 6 MiB
    float*          rinv = (float*)(ws + 140509184);            // 32 KiB

    cvt_x<<<8192, 256, 0, stream>>>(x, Xb);
    wt_kernel<<<dim3(32, 32, 3), 256, 0, stream>>>(Wq, Wk, Wv, Wt);

    gemm_nt<0><<<dim3(128, 16, 1), 256, 0, stream>>>(Xb, 1024, Wt, 1024, Q, nullptr);
    gemm_nt<0><<<dim3(128, 16, 1), 256, 0, stream>>>(Xb, 1024, Wt + 1048576, 1024, K, nullptr);
    gemm_nt<1><<<dim3(128, 16, 1), 256, 0, stream>>>(Xb, 1024, Wt + 2097152, 1024, Vt, nullptr);

    gemm_nt<2><<<dim3(32, 32, 4), 256, 0, stream>>>(Q, 1024, K, 1024, S, nullptr);
    softmax_rows<<<2048, 256, 0, stream>>>(S, rinv);
    gemm_nt<3><<<dim3(32, 16, 4), 256, 0, stream>>>((const __hip_bfloat16*)S, 4096, Vt, 2048,
                                                    d_out, rinv);
}

// Round 2
// 193.094 us; speedup vs baseline: 1.4928x; 1.4928x over previous
//
#include <hip/hip_runtime.h>
#include <hip/hip_bf16.h>
#include <stdint.h>

#define D_ 1024
#define NSEQ 2048

typedef __attribute__((ext_vector_type(8))) short bf16x8;
typedef __attribute__((ext_vector_type(4))) float f32x4;

static __device__ __forceinline__ unsigned short f2bf(float x) {
    union { __hip_bfloat16 h; unsigned short u; } cv;
    cv.h = __float2bfloat16(x);
    return cv.u;
}

// async global->LDS, 16B per lane. LDS dest must be wave-uniform base (+lane*16 by HW).
static __device__ __forceinline__ void gload_lds16(const void* g, void* l) {
    __builtin_amdgcn_global_load_lds(
        (const __attribute__((address_space(1))) unsigned int*)(uintptr_t)g,
        (__attribute__((address_space(3))) unsigned int*)(uintptr_t)l, 16, 0, 0);
}

// ---------------- x fp32 -> bf16 ----------------
__global__ __launch_bounds__(256) void cvt_x(const float* __restrict__ x,
                                             __hip_bfloat16* __restrict__ xb) {
    int i = blockIdx.x * 256 + threadIdx.x;
    float4 v = reinterpret_cast<const float4*>(x)[i];
    ushort4 o;
    o.x = f2bf(v.x); o.y = f2bf(v.y); o.z = f2bf(v.z); o.w = f2bf(v.w);
    reinterpret_cast<ushort4*>(xb)[i] = o;
}

// ---------------- W [d][e] fp32 -> Wt [e][d] bf16 (3 weights stacked -> [3072][1024]) ----------------
__global__ __launch_bounds__(256) void wt_kernel(const float* __restrict__ Wq,
                                                 const float* __restrict__ Wk,
                                                 const float* __restrict__ Wv,
                                                 __hip_bfloat16* __restrict__ Wt) {
    const float* W = (blockIdx.z == 0) ? Wq : (blockIdx.z == 1) ? Wk : Wv;
    unsigned short* O = (unsigned short*)(Wt + (size_t)blockIdx.z * D_ * D_);
    __shared__ float tile[32][33];
    int r0 = blockIdx.y * 32, c0 = blockIdx.x * 32;
    int t = threadIdx.x;
    int r = t >> 3, c4 = (t & 7) * 4;
    float4 v = *reinterpret_cast<const float4*>(&W[(size_t)(r0 + r) * D_ + c0 + c4]);
    tile[r][c4 + 0] = v.x; tile[r][c4 + 1] = v.y;
    tile[r][c4 + 2] = v.z; tile[r][c4 + 3] = v.w;
    __syncthreads();
    int er = t >> 3, dc = (t & 7) * 4;
    ushort4 pk;
    pk.x = f2bf(tile[dc + 0][er]); pk.y = f2bf(tile[dc + 1][er]);
    pk.z = f2bf(tile[dc + 2][er]); pk.w = f2bf(tile[dc + 3][er]);
    *reinterpret_cast<ushort4*>(&O[(size_t)(c0 + er) * D_ + r0 + dc]) = pk;
}

// ---------------- NT GEMM, 128x128 tile, BK=32, 4 waves (2x2), 4x4 frags/wave ----------------
// MODE 0: fused QKV epilogue (o0=Q row-major, o1=K row-major, o2=Vt transposed per batch)
// MODE 2: scores fp32 *1/32, causal mask, skip by>bx, per-batch z  (o0=S)
// MODE 3: PV, Kdim=(bx+1)*128, out fp32 * rinv[q]                  (o0=out)
template <int MODE>
__global__ __launch_bounds__(256) void gemm128(const __hip_bfloat16* __restrict__ A, int lda,
                                               const __hip_bfloat16* __restrict__ Bt, int ldb,
                                               void* __restrict__ o0, void* __restrict__ o1,
                                               void* __restrict__ o2,
                                               const float* __restrict__ rinv) {
    const int bx = blockIdx.x, by = blockIdx.y, bz = blockIdx.z;
    if (MODE == 2 && by > bx) return;    // fully masked tile, never read downstream

    const __hip_bfloat16* Ab = A;
    const __hip_bfloat16* Bb = Bt;
    int Kdim = 1024;
    if (MODE == 2) { Ab += (size_t)bz * NSEQ * D_;  Bb += (size_t)bz * NSEQ * D_; }
    if (MODE == 3) { Ab += (size_t)bz * NSEQ * 4096; Bb += (size_t)bz * D_ * NSEQ; Kdim = (bx + 1) * 128; }

    const int m0 = bx * 128, n0 = by * 128;

    __shared__ __hip_bfloat16 As[128 * 32];   // linear [128][32], row stride 64B
    __shared__ __hip_bfloat16 Bs[128 * 32];

    const int tid = threadIdx.x;
    const int lane = tid & 63, wid = tid >> 6;
    const int wm = wid >> 1, wn = wid & 1;
    const int lr = lane & 15, lk = lane >> 4;

    // staging: wave w covers rows [w*32, w*32+32), two 1024B insts of 16 rows each
    const int srow = wid * 32 + (lane >> 2);
    const int scol = (lane & 3) * 8;
    const __hip_bfloat16* aptr = Ab + (size_t)(m0 + srow) * lda + scol;
    const __hip_bfloat16* bptr = Bb + (size_t)(n0 + srow) * ldb + scol;
    char* AsW = (char*)As + wid * 2048;
    char* BsW = (char*)Bs + wid * 2048;

    f32x4 acc[4][4] = {};

    for (int k0 = 0; k0 < Kdim; k0 += 32) {
        gload_lds16(aptr,                    AsW);
        gload_lds16(aptr + (size_t)16 * lda, AsW + 1024);
        gload_lds16(bptr,                    BsW);
        gload_lds16(bptr + (size_t)16 * ldb, BsW + 1024);
        aptr += 32; bptr += 32;
        __syncthreads();   // drains vmcnt (loads landed) + barrier

        bf16x8 af[4], bfr[4];
#pragma unroll
        for (int m = 0; m < 4; ++m)
            af[m] = *reinterpret_cast<const bf16x8*>(&As[(wm * 64 + m * 16 + lr) * 32 + lk * 8]);
#pragma unroll
        for (int n = 0; n < 4; ++n)
            bfr[n] = *reinterpret_cast<const bf16x8*>(&Bs[(wn * 64 + n * 16 + lr) * 32 + lk * 8]);
#pragma unroll
        for (int m = 0; m < 4; ++m)
#pragma unroll
            for (int n = 0; n < 4; ++n)
                acc[m][n] = __builtin_amdgcn_mfma_f32_16x16x32_bf16(af[m], bfr[n], acc[m][n], 0, 0, 0);
        __syncthreads();   // all reads done before next-iter staging overwrites
    }

#pragma unroll
    for (int m = 0; m < 4; ++m)
#pragma unroll
        for (int n = 0; n < 4; ++n) {
            const int rbase = m0 + wm * 64 + m * 16 + lk * 4;   // +j
            const int cbase = n0 + wn * 64 + n * 16 + lr;
            if (MODE == 0) {
                const int seg = cbase >> 10, e = cbase & 1023;
                if (seg < 2) {
                    unsigned short* C = (unsigned short*)(seg == 0 ? o0 : o1);
#pragma unroll
                    for (int j = 0; j < 4; ++j)
                        C[(size_t)(rbase + j) * D_ + e] = f2bf(acc[m][n][j]);
                } else {
                    unsigned short* Vt = (unsigned short*)o2;
                    const int b = rbase >> 11, nq = rbase & 2047;
                    ushort4 pk;
                    pk.x = f2bf(acc[m][n][0]); pk.y = f2bf(acc[m][n][1]);
                    pk.z = f2bf(acc[m][n][2]); pk.w = f2bf(acc[m][n][3]);
                    *reinterpret_cast<ushort4*>(&Vt[(((size_t)b << 10) + e) * NSEQ + nq]) = pk;
                }
            } else if (MODE == 2) {
                float* S = (float*)o0 + (size_t)bz * NSEQ * NSEQ;
#pragma unroll
                for (int j = 0; j < 4; ++j) {
                    const int qg = rbase + j, kg = cbase;
                    float s = acc[m][n][j] * 0.03125f;   // 1/sqrt(1024)
                    if (kg > qg) s = -1e30f;
                    S[(size_t)qg * NSEQ + kg] = s;
                }
            } else if (MODE == 3) {
                float* O = (float*)o0 + (size_t)bz * NSEQ * D_;
#pragma unroll
                for (int j = 0; j < 4; ++j)
                    O[(size_t)(rbase + j) * D_ + cbase] =
                        acc[m][n][j] * rinv[bz * NSEQ + rbase + j];
            }
        }
}

// ---------------- row softmax (128-col granularity), unnormalized P bf16 in place ----------------
__global__ __launch_bounds__(256) void softmax_rows(float* __restrict__ S,
                                                    float* __restrict__ rinv) {
    int lane = threadIdx.x & 63;
    int row = blockIdx.x * 4 + (threadIdx.x >> 6);   // 0..8191
    int q = row & 2047;
    float* srow = S + (size_t)row * NSEQ;
    int L = ((q >> 7) + 1) << 7;                     // matches 128-block causal granularity

    float mx = -1e30f;
    for (int k = lane * 4; k < L; k += 256) {
        float4 v = *reinterpret_cast<const float4*>(srow + k);
        mx = fmaxf(mx, fmaxf(fmaxf(v.x, v.y), fmaxf(v.z, v.w)));
    }
    for (int off = 32; off > 0; off >>= 1) mx = fmaxf(mx, __shfl_xor(mx, off, 64));

    float sum = 0.f;
    unsigned short* prow = (unsigned short*)srow;    // in-place: bf16 writes trail fp32 reads
    for (int k = lane * 4; k < L; k += 256) {
        float4 v = *reinterpret_cast<const float4*>(srow + k);
        float e0 = __expf(v.x - mx), e1 = __expf(v.y - mx);
        float e2 = __expf(v.z - mx), e3 = __expf(v.w - mx);
        sum += (e0 + e1) + (e2 + e3);
        ushort4 pk; pk.x = f2bf(e0); pk.y = f2bf(e1); pk.z = f2bf(e2); pk.w = f2bf(e3);
        *reinterpret_cast<ushort4*>(prow + k) = pk;
    }
    for (int off = 32; off > 0; off >>= 1) sum += __shfl_xor(sum, off, 64);
    if (lane == 0) rinv[row] = 1.0f / sum;
}

extern "C" void kernel_launch(void* const* d_in, const int* in_sizes, int n_in,
                              void* d_out, int out_size, void* d_ws, size_t ws_size,
                              hipStream_t stream) {
    const float* x  = (const float*)d_in[0];
    const float* Wq = (const float*)d_in[1];
    const float* Wk = (const float*)d_in[2];
    const float* Wv = (const float*)d_in[3];

    char* ws = (char*)d_ws;
    float*          S    = (float*)(ws);                        // 64 MiB
    __hip_bfloat16* Xb   = (__hip_bfloat16*)(ws + 67108864);    // 16 MiB
    __hip_bfloat16* Q    = (__hip_bfloat16*)(ws + 83886080);    // 16 MiB
    __hip_bfloat16* K    = (__hip_bfloat16*)(ws + 100663296);   // 16 MiB
    __hip_bfloat16* Vt   = (__hip_bfloat16*)(ws + 117440512);   // 16 MiB
    __hip_bfloat16* Wt   = (__hip_bfloat16*)(ws + 134217728);   // 6 MiB
    float*          rinv = (float*)(ws + 140509184);            // 32 KiB

    cvt_x<<<8192, 256, 0, stream>>>(x, Xb);
    wt_kernel<<<dim3(32, 32, 3), 256, 0, stream>>>(Wq, Wk, Wv, Wt);

    // fused QKV: [8192,1024] x [3072,1024]^T
    gemm128<0><<<dim3(64, 24, 1), 256, 0, stream>>>(Xb, 1024, Wt, 1024, Q, K, Vt, nullptr);
    // scores
    gemm128<2><<<dim3(16, 16, 4), 256, 0, stream>>>(Q, 1024, K, 1024, S, nullptr, nullptr, nullptr);
    softmax_rows<<<2048, 256, 0, stream>>>(S, rinv);
    // PV
    gemm128<3><<<dim3(16, 8, 4), 256, 0, stream>>>((const __hip_bfloat16*)S, 4096, Vt, 2048,
                                                   d_out, nullptr, nullptr, rinv);
}